// Round 1
// baseline (2268.911 us; speedup 1.0000x reference)
//
#include <hip/hip_runtime.h>

#define IN_CH   32
#define OUT_CH  64
#define FEAT_CH 256
#define PTOT    32768   // S*OUT_H*OUT_W
#define CTOT    90688
// layer offsets inside one tile's feat vector
#define BEG1    0
#define BIAS1   8192
#define BEG2    8448
#define BIAS2   73984
#define BEG3    74240
#define BIAS3   90624

// ---------------- Stage A: feat[n][c] = w_feat[c,:] . mlp[b,:,a] + b_feat[c]
// n = b*64 + a (a = h*8+w). One block = 64 c-rows, 256 threads = 256 columns.
__global__ __launch_bounds__(256) void feat_gemm(
    const float* __restrict__ w_feat, const float* __restrict__ b_feat,
    const float* __restrict__ mlp, float* __restrict__ feat) {
  const int tid = threadIdx.x;
  const int n = tid;
  const int b = n >> 6, a = n & 63;
  const float* __restrict__ mv = mlp + (size_t)b * (FEAT_CH * 64) + a;
  const int c0 = blockIdx.x * 64;
  float acc[64];
#pragma unroll
  for (int c = 0; c < 64; ++c) acc[c] = 0.f;
  for (int kc = 0; kc < FEAT_CH; kc += 32) {   // 8 runtime iters
    float m[32];
#pragma unroll
    for (int k = 0; k < 32; ++k) m[k] = mv[(size_t)(kc + k) * 64];
#pragma unroll
    for (int c = 0; c < 64; ++c) {
      const float* __restrict__ wr = w_feat + (size_t)(c0 + c) * FEAT_CH + kc;  // wave-uniform -> s_load
#pragma unroll
      for (int k = 0; k < 32; ++k) acc[c] = fmaf(wr[k], m[k], acc[c]);
    }
  }
  float* __restrict__ dst = feat + (size_t)n * CTOT + c0;
#pragma unroll
  for (int c = 0; c < 64; ++c) dst[c] = acc[c] + b_feat[c0 + c];
}

// ---------------- Stage B: xin[tile][pp][i] = coord_em + w_cd . coord_data
__global__ __launch_bounds__(256) void coord_prep(
    const float* __restrict__ coord_em, const float* __restrict__ coord_dt,
    const float* __restrict__ w_cd, const float* __restrict__ b_cd,
    float* __restrict__ xin) {
  const int gid = blockIdx.x * 256 + threadIdx.x;
  const int b = gid >> 15;
  const int p = gid & 32767;
  const float* __restrict__ cdr = coord_dt + ((size_t)b * PTOT + p) * OUT_CH;
  float acc[IN_CH];
#pragma unroll
  for (int o = 0; o < IN_CH; ++o) acc[o] = 0.f;
  for (int ic = 0; ic < OUT_CH; ic += 16) {    // 4 runtime iters
    float x[16];
#pragma unroll
    for (int j = 0; j < 16; j += 4) {
      float4 v = *(const float4*)(cdr + ic + j);
      x[j] = v.x; x[j + 1] = v.y; x[j + 2] = v.z; x[j + 3] = v.w;
    }
#pragma unroll
    for (int o = 0; o < IN_CH; ++o) {
#pragma unroll
      for (int j = 0; j < 16; ++j)
        acc[o] = fmaf(w_cd[o * OUT_CH + ic + j], x[j], acc[o]);  // uniform -> s_load
    }
  }
#pragma unroll
  for (int o = 0; o < IN_CH; ++o)
    acc[o] += b_cd[o] + coord_em[((size_t)b * IN_CH + o) * PTOT + p];
  // p -> (s, ah, ph, aw, pw); pp = s*64 + ph*8 + pw; tile = b*64 + ah*8+aw
  const int s = p >> 12, rem = p & 4095;
  const int oh = rem >> 6, ow = rem & 63;
  const int a = ((oh >> 3) << 3) | (ow >> 3);
  const int pp = (s << 6) | ((oh & 7) << 3) | (ow & 7);
  float* __restrict__ dst = xin + ((size_t)(b * 64 + a) * 512 + pp) * IN_CH;
#pragma unroll
  for (int o = 0; o < IN_CH; o += 4)
    *(float4*)(dst + o) = make_float4(acc[o], acc[o + 1], acc[o + 2], acc[o + 3]);
}

// ---------------- Stage C: per-tile MLP, lane = row, wave = column group
template <int DIN, int DOUT, int INSTR>
__device__ __forceinline__ void mlp_layer(
    const float* __restrict__ W, const float* __restrict__ bias,
    const float (*__restrict__ in)[INSTR], float (*__restrict__ outb)[257],
    int lane, int wv, bool relu) {
  const int CPW = DOUT / 8;
  float acc[CPW];
#pragma unroll
  for (int oc = 0; oc < CPW; ++oc) acc[oc] = 0.f;
  for (int ic = 0; ic < DIN; ic += 8) {
    float xv[8];
#pragma unroll
    for (int j = 0; j < 8; ++j) xv[j] = in[lane][ic + j];
#pragma unroll
    for (int oc = 0; oc < CPW; ++oc) {
      const float* __restrict__ wr = W + (wv * CPW + oc) * DIN + ic;  // wave-uniform -> s_load
#pragma unroll
      for (int j = 0; j < 8; ++j) acc[oc] = fmaf(wr[j], xv[j], acc[oc]);
    }
  }
#pragma unroll
  for (int oc = 0; oc < CPW; ++oc) {
    const int o = wv * CPW + oc;
    float v = acc[oc] + bias[o];
    if (relu) v = v >= 0.f ? v : 0.01f * v;
    outb[lane][o] = v;
  }
}

__global__ __launch_bounds__(512) void tile_mlp(
    const float* __restrict__ feat, const float* __restrict__ xin,
    float* __restrict__ out) {
  __shared__ float xbuf[64][33];    // +1 pad: bank = (lane+i)%32, conflict-free
  __shared__ float h1[64][257];
  __shared__ float h2[64][257];
  const int tile = blockIdx.x;
  const int b = tile >> 6, a = tile & 63;
  const int ah = a >> 3, aw = a & 7;
  const int tid = threadIdx.x;
  const int lane = tid & 63;
  const int wv = __builtin_amdgcn_readfirstlane(tid >> 6);  // force uniform
  const float* __restrict__ F = feat + (size_t)tile * CTOT;

  for (int chunk = 0; chunk < 8; ++chunk) {
    {  // stage x chunk: 64 rows x 32 ch = 512 float4
      const float4* __restrict__ src =
          (const float4*)(xin + ((size_t)tile * 512 + chunk * 64) * IN_CH);
      float4 v = src[tid];
      const int r = tid >> 3, i4 = (tid & 7) << 2;
      xbuf[r][i4 + 0] = v.x; xbuf[r][i4 + 1] = v.y;
      xbuf[r][i4 + 2] = v.z; xbuf[r][i4 + 3] = v.w;
    }
    __syncthreads();
    mlp_layer<32, 256, 33>(F + BEG1, F + BIAS1, xbuf, h1, lane, wv, true);
    __syncthreads();
    mlp_layer<256, 256, 257>(F + BEG2, F + BIAS2, h1, h2, lane, wv, true);
    __syncthreads();
    {  // layer 3 (dout=64) -> global, with output layout transform
      float acc[8];
#pragma unroll
      for (int oc = 0; oc < 8; ++oc) acc[oc] = 0.f;
      for (int ic = 0; ic < 256; ic += 8) {
        float xv[8];
#pragma unroll
        for (int j = 0; j < 8; ++j) xv[j] = h2[lane][ic + j];
#pragma unroll
        for (int oc = 0; oc < 8; ++oc) {
          const float* __restrict__ wr = F + BEG3 + (wv * 8 + oc) * 256 + ic;
#pragma unroll
          for (int j = 0; j < 8; ++j) acc[oc] = fmaf(wr[j], xv[j], acc[oc]);
        }
      }
      const int s = chunk;
      const int ph = (lane >> 3) & 7, pw = lane & 7;
      const int row = (ah * 8 + ph) * 64 + (aw * 8 + pw);
#pragma unroll
      for (int oc = 0; oc < 8; ++oc) {
        const int o = wv * 8 + oc;
        out[(((size_t)(b * 64 + o)) * 8 + s) * 4096 + row] = acc[oc] + F[BIAS3 + o];
      }
    }
    __syncthreads();
  }
}

extern "C" void kernel_launch(void* const* d_in, const int* in_sizes, int n_in,
                              void* d_out, int out_size, void* d_ws, size_t ws_size,
                              hipStream_t stream) {
  const float* mlp      = (const float*)d_in[0];
  const float* coord_em = (const float*)d_in[1];
  const float* coord_dt = (const float*)d_in[2];
  const float* w_cd     = (const float*)d_in[3];
  const float* b_cd     = (const float*)d_in[4];
  const float* w_feat   = (const float*)d_in[5];
  const float* b_feat   = (const float*)d_in[6];
  float* out = (float*)d_out;
  float* feat = (float*)d_ws;                                // 256*90688*4 = 92,864,512 B
  float* xin  = (float*)((char*)d_ws + 92864512ull);         // +16,777,216 B

  feat_gemm<<<CTOT / 64, 256, 0, stream>>>(w_feat, b_feat, mlp, feat);
  coord_prep<<<(4 * PTOT) / 256, 256, 0, stream>>>(coord_em, coord_dt, w_cd, b_cd, xin);
  tile_mlp<<<256, 512, 0, stream>>>(feat, xin, out);
}

// Round 2
// 314.676 us; speedup vs baseline: 7.2103x; 7.2103x over previous
//
#include <hip/hip_runtime.h>

typedef __attribute__((ext_vector_type(8))) short bf16x8;
typedef __attribute__((ext_vector_type(4))) float f32x4;

#define IN_CH   32
#define OUT_CH  64
#define FEAT_CH 256
#define PTOT    32768
#define CTOT    90688
#define BEG1    0
#define BIAS1   8192
#define BEG2    8448
#define BIAS2   73984
#define BEG3    74240
#define BIAS3   90624

__device__ __forceinline__ short f2bf(float f) {          // RNE via hw cvt
  __bf16 h = (__bf16)f;
  return __builtin_bit_cast(short, h);
}
__device__ __forceinline__ float bf2f(unsigned short h) {
  union { unsigned u; float f; } v; v.u = ((unsigned)h) << 16;
  return v.f;
}

// ================= Stage A: featb[n][c] = bf16( w_feat[c,:] . mlpvec[:,n] + b_feat[c] )
// M = c (90688, padded to 709*128), N = n = b*64+a (panel of 128 per blockIdx.y), K = 256.
__global__ __launch_bounds__(512, 4) void feat_gemm_mfma(
    const float* __restrict__ w_feat, const float* __restrict__ b_feat,
    const float* __restrict__ mlp, unsigned short* __restrict__ featb) {
  __shared__ unsigned short mlpb[128][264];   // [n'][k], row stride 528B = 4 banks offset
  const int tid = threadIdx.x;
  const int lane = tid & 63;
  const int wv = tid >> 6;
  const int m0 = blockIdx.x * 128;
  const int by = blockIdx.y;
  {  // stage mlpb[n'][k] = bf16(mlp[b][k][a]); coalesced along a
    const int np = tid & 127;
    const int n = by * 128 + np;
    const int b = n >> 6, a = n & 63;
    const int k0 = (tid >> 7) * 64;
    const float* __restrict__ src = mlp + (size_t)b * (FEAT_CH * 64) + a;
#pragma unroll 8
    for (int kk = 0; kk < 64; ++kk) {
      const int k = k0 + kk;
      mlpb[np][k] = (unsigned short)f2bf(src[(size_t)k * 64]);
    }
  }
  __syncthreads();
  const int wr = wv & 3, wc = wv >> 2;        // 4 m-groups x 2 n-groups
  const int l15 = lane & 15, l4 = lane >> 4;
  f32x4 acc[2][4];
#pragma unroll
  for (int mf = 0; mf < 2; ++mf)
#pragma unroll
    for (int nf = 0; nf < 4; ++nf) acc[mf][nf] = f32x4{0.f, 0.f, 0.f, 0.f};
#pragma unroll
  for (int ks = 0; ks < 8; ++ks) {
    bf16x8 A[2], Bv[4];
#pragma unroll
    for (int mf = 0; mf < 2; ++mf) {
      int row = m0 + wr * 32 + mf * 16 + l15;
      if (row >= CTOT) row = CTOT - 1;        // clamp; writes guarded below
      const float* __restrict__ wp = w_feat + (size_t)row * 256 + ks * 32 + l4 * 8;
      const float4 p0 = *(const float4*)wp, p1 = *(const float4*)(wp + 4);
      bf16x8 t;
      t[0] = f2bf(p0.x); t[1] = f2bf(p0.y); t[2] = f2bf(p0.z); t[3] = f2bf(p0.w);
      t[4] = f2bf(p1.x); t[5] = f2bf(p1.y); t[6] = f2bf(p1.z); t[7] = f2bf(p1.w);
      A[mf] = t;
    }
#pragma unroll
    for (int nf = 0; nf < 4; ++nf)
      Bv[nf] = *(const bf16x8*)&mlpb[wc * 64 + nf * 16 + l15][ks * 32 + l4 * 8];
#pragma unroll
    for (int mf = 0; mf < 2; ++mf)
#pragma unroll
      for (int nf = 0; nf < 4; ++nf)
        acc[mf][nf] = __builtin_amdgcn_mfma_f32_16x16x32_bf16(A[mf], Bv[nf], acc[mf][nf], 0, 0, 0);
  }
#pragma unroll
  for (int mf = 0; mf < 2; ++mf) {
    const int c = m0 + wr * 32 + mf * 16 + l4 * 4;   // 4 consecutive c per lane (regs)
    if (c < CTOT) {
      const float4 bia = *(const float4*)&b_feat[c];
#pragma unroll
      for (int nf = 0; nf < 4; ++nf) {
        const int n = by * 128 + wc * 64 + nf * 16 + l15;
        ushort4 o;
        o.x = (unsigned short)f2bf(acc[mf][nf][0] + bia.x);
        o.y = (unsigned short)f2bf(acc[mf][nf][1] + bia.y);
        o.z = (unsigned short)f2bf(acc[mf][nf][2] + bia.z);
        o.w = (unsigned short)f2bf(acc[mf][nf][3] + bia.w);
        *(ushort4*)(featb + (size_t)n * CTOT + c) = o;
      }
    }
  }
}

// ================= Stage B: xinb[tile][pp][i] = bf16(coord_em + w_cd . coord_data)
__global__ __launch_bounds__(256) void coord_prep(
    const float* __restrict__ coord_em, const float* __restrict__ coord_dt,
    const float* __restrict__ w_cd, const float* __restrict__ b_cd,
    unsigned short* __restrict__ xinb) {
  const int gid = blockIdx.x * 256 + threadIdx.x;
  const int b = gid >> 15;
  const int p = gid & 32767;
  const float* __restrict__ cdr = coord_dt + ((size_t)b * PTOT + p) * OUT_CH;
  float acc[IN_CH];
#pragma unroll
  for (int o = 0; o < IN_CH; ++o) acc[o] = 0.f;
  for (int ic = 0; ic < OUT_CH; ic += 16) {
    float x[16];
#pragma unroll
    for (int j = 0; j < 16; j += 4) {
      float4 v = *(const float4*)(cdr + ic + j);
      x[j] = v.x; x[j + 1] = v.y; x[j + 2] = v.z; x[j + 3] = v.w;
    }
#pragma unroll
    for (int o = 0; o < IN_CH; ++o) {
#pragma unroll
      for (int j = 0; j < 16; ++j)
        acc[o] = fmaf(w_cd[o * OUT_CH + ic + j], x[j], acc[o]);  // uniform -> s_load
    }
  }
#pragma unroll
  for (int o = 0; o < IN_CH; ++o)
    acc[o] += b_cd[o] + coord_em[((size_t)b * IN_CH + o) * PTOT + p];
  const int s = p >> 12, rem = p & 4095;
  const int oh = rem >> 6, ow = rem & 63;
  const int a = ((oh >> 3) << 3) | (ow >> 3);
  const int pp = (s << 6) | ((oh & 7) << 3) | (ow & 7);
  unsigned short* __restrict__ dst = xinb + ((size_t)((b << 6) + a) * 512 + pp) * IN_CH;
#pragma unroll
  for (int o = 0; o < IN_CH; o += 4) {
    ushort4 v;
    v.x = (unsigned short)f2bf(acc[o]);     v.y = (unsigned short)f2bf(acc[o + 1]);
    v.z = (unsigned short)f2bf(acc[o + 2]); v.w = (unsigned short)f2bf(acc[o + 3]);
    *(ushort4*)(dst + o) = v;
  }
}

// ================= Stage C: per-tile MLP via MFMA. Block = quarter tile (128 rows, 2 chunks of 64).
__global__ __launch_bounds__(512, 4) void tile_mlp(
    const unsigned short* __restrict__ featb, const unsigned short* __restrict__ xinb,
    float* __restrict__ out) {
  __shared__ unsigned short xch[64][40];    // row stride 80B: 2-way bank alias (free), 16B-aligned
  __shared__ unsigned short h1[64][264];    // row stride 528B = +4 banks/row, 16B-aligned
  __shared__ unsigned short h2[64][264];
  const int tile = blockIdx.x >> 2;
  const int part = blockIdx.x & 3;
  const int b = tile >> 6, a = tile & 63;
  const int ah = a >> 3, aw = a & 7;
  const int tid = threadIdx.x;
  const int lane = tid & 63;
  const int wv = tid >> 6;
  const int wr = wv & 1, wc = wv >> 1;      // 2 row-groups(32) x 4 col-groups(64)
  const int l15 = lane & 15, l4 = lane >> 4;
  const unsigned short* __restrict__ F = featb + (size_t)tile * CTOT;

  float b1[4], b2[4];
#pragma unroll
  for (int nf = 0; nf < 4; ++nf) {
    b1[nf] = bf2f(F[BIAS1 + wc * 64 + nf * 16 + l15]);
    b2[nf] = bf2f(F[BIAS2 + wc * 64 + nf * 16 + l15]);
  }
  const float b3 = bf2f(F[BIAS3 + wc * 16 + l15]);

  for (int ch = 0; ch < 2; ++ch) {
    const int row0 = part * 128 + ch * 64;
    {  // stage x chunk: 64 rows x 32 ch bf16
      const unsigned short* __restrict__ src = xinb + ((size_t)tile * 512 + row0) * IN_CH;
      const int r = tid >> 3, c4 = (tid & 7) * 4;
      *(ushort4*)&xch[r][c4] = *(const ushort4*)(src + r * 32 + c4);
    }
    __syncthreads();
    // ---- layer 1: 64x256, K=32 (one k-step)
    f32x4 acc1[2][4];
#pragma unroll
    for (int mf = 0; mf < 2; ++mf)
#pragma unroll
      for (int nf = 0; nf < 4; ++nf) acc1[mf][nf] = f32x4{0.f, 0.f, 0.f, 0.f};
    {
      bf16x8 A[2];
#pragma unroll
      for (int mf = 0; mf < 2; ++mf)
        A[mf] = *(const bf16x8*)&xch[wr * 32 + mf * 16 + l15][l4 * 8];
#pragma unroll
      for (int nf = 0; nf < 4; ++nf) {
        const bf16x8 Bv = *(const bf16x8*)(F + BEG1 + (size_t)(wc * 64 + nf * 16 + l15) * 32 + l4 * 8);
#pragma unroll
        for (int mf = 0; mf < 2; ++mf)
          acc1[mf][nf] = __builtin_amdgcn_mfma_f32_16x16x32_bf16(A[mf], Bv, acc1[mf][nf], 0, 0, 0);
      }
    }
#pragma unroll
    for (int mf = 0; mf < 2; ++mf)
#pragma unroll
      for (int nf = 0; nf < 4; ++nf)
#pragma unroll
        for (int r = 0; r < 4; ++r) {
          float v = acc1[mf][nf][r] + b1[nf];
          v = v >= 0.f ? v : 0.01f * v;
          h1[wr * 32 + mf * 16 + l4 * 4 + r][wc * 64 + nf * 16 + l15] = (unsigned short)f2bf(v);
        }
    __syncthreads();
    // ---- layer 2: 64x256, K=256
    f32x4 acc2[2][4];
#pragma unroll
    for (int mf = 0; mf < 2; ++mf)
#pragma unroll
      for (int nf = 0; nf < 4; ++nf) acc2[mf][nf] = f32x4{0.f, 0.f, 0.f, 0.f};
#pragma unroll
    for (int ks = 0; ks < 8; ++ks) {
      bf16x8 A2[2], B2[4];
#pragma unroll
      for (int mf = 0; mf < 2; ++mf)
        A2[mf] = *(const bf16x8*)&h1[wr * 32 + mf * 16 + l15][ks * 32 + l4 * 8];
#pragma unroll
      for (int nf = 0; nf < 4; ++nf)
        B2[nf] = *(const bf16x8*)(F + BEG2 + (size_t)(wc * 64 + nf * 16 + l15) * 256 + ks * 32 + l4 * 8);
#pragma unroll
      for (int mf = 0; mf < 2; ++mf)
#pragma unroll
        for (int nf = 0; nf < 4; ++nf)
          acc2[mf][nf] = __builtin_amdgcn_mfma_f32_16x16x32_bf16(A2[mf], B2[nf], acc2[mf][nf], 0, 0, 0);
    }
#pragma unroll
    for (int mf = 0; mf < 2; ++mf)
#pragma unroll
      for (int nf = 0; nf < 4; ++nf)
#pragma unroll
        for (int r = 0; r < 4; ++r) {
          float v = acc2[mf][nf][r] + b2[nf];
          v = v >= 0.f ? v : 0.01f * v;
          h2[wr * 32 + mf * 16 + l4 * 4 + r][wc * 64 + nf * 16 + l15] = (unsigned short)f2bf(v);
        }
    __syncthreads();
    // ---- layer 3: 64x64, K=256, fp32 out with layout transform
    f32x4 acc3[2];
#pragma unroll
    for (int mf = 0; mf < 2; ++mf) acc3[mf] = f32x4{0.f, 0.f, 0.f, 0.f};
#pragma unroll
    for (int ks = 0; ks < 8; ++ks) {
      const bf16x8 B3 = *(const bf16x8*)(F + BEG3 + (size_t)(wc * 16 + l15) * 256 + ks * 32 + l4 * 8);
#pragma unroll
      for (int mf = 0; mf < 2; ++mf) {
        const bf16x8 A3 = *(const bf16x8*)&h2[wr * 32 + mf * 16 + l15][ks * 32 + l4 * 8];
        acc3[mf] = __builtin_amdgcn_mfma_f32_16x16x32_bf16(A3, B3, acc3[mf], 0, 0, 0);
      }
    }
    {
      const int o = wc * 16 + l15;
      const int s = part * 2 + ch;
#pragma unroll
      for (int mf = 0; mf < 2; ++mf) {
        const int ml = wr * 32 + mf * 16 + l4 * 4;   // local row; +r over regs
        const int ph = ml >> 3, pwb = ml & 7;        // pwb in {0,4} -> float4 aligned
        float4 v;
        v.x = acc3[mf][0] + b3; v.y = acc3[mf][1] + b3;
        v.z = acc3[mf][2] + b3; v.w = acc3[mf][3] + b3;
        *(float4*)&out[((size_t)((b * 64 + o) * 8 + s)) * 4096 +
                       (ah * 8 + ph) * 64 + aw * 8 + pwb] = v;
      }
    }
    __syncthreads();
  }
}

extern "C" void kernel_launch(void* const* d_in, const int* in_sizes, int n_in,
                              void* d_out, int out_size, void* d_ws, size_t ws_size,
                              hipStream_t stream) {
  const float* mlp      = (const float*)d_in[0];
  const float* coord_em = (const float*)d_in[1];
  const float* coord_dt = (const float*)d_in[2];
  const float* w_cd     = (const float*)d_in[3];
  const float* b_cd     = (const float*)d_in[4];
  const float* w_feat   = (const float*)d_in[5];
  const float* b_feat   = (const float*)d_in[6];
  float* out = (float*)d_out;
  unsigned short* featb = (unsigned short*)d_ws;                       // 46,432,256 B
  unsigned short* xinb  = (unsigned short*)((char*)d_ws + 46432256ull); // 8,388,608 B

  feat_gemm_mfma<<<dim3(709, 2), 512, 0, stream>>>(w_feat, b_feat, mlp, featb);
  coord_prep<<<512, 256, 0, stream>>>(coord_em, coord_dt, w_cd, b_cd, xinb);
  tile_mlp<<<1024, 512, 0, stream>>>(featb, xinb, out);
}

// Round 3
// 248.275 us; speedup vs baseline: 9.1387x; 1.2675x over previous
//
#include <hip/hip_runtime.h>

typedef __attribute__((ext_vector_type(8))) short bf16x8;
typedef __attribute__((ext_vector_type(8))) unsigned short ushort8;
typedef __attribute__((ext_vector_type(4))) float f32x4;

#define IN_CH   32
#define OUT_CH  64
#define FEAT_CH 256
#define PTOT    32768
#define CTOT    90688
#define BEG1    0
#define BIAS1   8192
#define BEG2    8448
#define BIAS2   73984
#define BEG3    74240
#define BIAS3   90624

__device__ __forceinline__ unsigned short f2bf(float f) {
  __bf16 h = (__bf16)f;
  return __builtin_bit_cast(unsigned short, h);
}
__device__ __forceinline__ float bf2f(unsigned short h) {
  union { unsigned u; float f; } v; v.u = ((unsigned)h) << 16;
  return v.f;
}

// ============ mlp transpose: mlpT[n][k] = bf16(mlp[b][k][a]), n = b*64+a
__global__ __launch_bounds__(256) void mlp_tr(
    const float* __restrict__ mlp, unsigned short* __restrict__ mlpT) {
  __shared__ float t[64][65];
  const int b = blockIdx.x >> 2, k0 = (blockIdx.x & 3) << 6;
  const int tid = threadIdx.x;
  const int a = tid & 63, kq = tid >> 6;
#pragma unroll
  for (int j = 0; j < 16; ++j) {
    const int k = kq * 16 + j;
    t[k][a] = mlp[(size_t)b * 16384 + (size_t)(k0 + k) * 64 + a];
  }
  __syncthreads();
  const int a2 = tid >> 2, c4 = tid & 3;
  ushort8 o0, o1;
#pragma unroll
  for (int j = 0; j < 8; ++j)  o0[j] = f2bf(t[c4 * 16 + j][a2]);
#pragma unroll
  for (int j = 0; j < 8; ++j)  o1[j] = f2bf(t[c4 * 16 + 8 + j][a2]);
  unsigned short* dst = mlpT + (size_t)(b * 64 + a2) * 256 + k0 + c4 * 16;
  *(ushort8*)dst = o0;
  *(ushort8*)(dst + 8) = o1;
}

// ============ Stage A: featb[n][c] = bf16(w_feat[c,:].mlpT[n,:] + b_feat[c])
// block: c-panel of 128 (bx), all 256 n. waves: 4 c-groups(32) x 2 n-groups(128).
__global__ __launch_bounds__(512, 2) void feat_gemm_mfma(
    const float* __restrict__ w_feat, const float* __restrict__ b_feat,
    const unsigned short* __restrict__ mlpT, unsigned short* __restrict__ featb) {
  const int tid = threadIdx.x;
  const int lane = tid & 63;
  const int wv = tid >> 6;
  const int wr = wv & 3, wc = wv >> 2;
  const int l15 = lane & 15, l4 = lane >> 4;
  const int m0 = blockIdx.x * 128;
  f32x4 acc[2][8];
#pragma unroll
  for (int mf = 0; mf < 2; ++mf)
#pragma unroll
    for (int nf = 0; nf < 8; ++nf) acc[mf][nf] = f32x4{0.f, 0.f, 0.f, 0.f};
#pragma unroll 2
  for (int ks = 0; ks < 8; ++ks) {
    bf16x8 A[2];
#pragma unroll
    for (int mf = 0; mf < 2; ++mf) {
      int row = m0 + wr * 32 + mf * 16 + l15;
      if (row >= CTOT) row = CTOT - 1;
      const float* __restrict__ wp = w_feat + (size_t)row * 256 + ks * 32 + l4 * 8;
      const float4 p0 = *(const float4*)wp, p1 = *(const float4*)(wp + 4);
      bf16x8 tv;
      tv[0] = f2bf(p0.x); tv[1] = f2bf(p0.y); tv[2] = f2bf(p0.z); tv[3] = f2bf(p0.w);
      tv[4] = f2bf(p1.x); tv[5] = f2bf(p1.y); tv[6] = f2bf(p1.z); tv[7] = f2bf(p1.w);
      A[mf] = tv;
    }
#pragma unroll
    for (int nf = 0; nf < 8; ++nf) {
      const bf16x8 Bv = *(const bf16x8*)(mlpT + (size_t)(wc * 128 + nf * 16 + l15) * 256 + ks * 32 + l4 * 8);
#pragma unroll
      for (int mf = 0; mf < 2; ++mf)
        acc[mf][nf] = __builtin_amdgcn_mfma_f32_16x16x32_bf16(A[mf], Bv, acc[mf][nf], 0, 0, 0);
    }
  }
#pragma unroll
  for (int mf = 0; mf < 2; ++mf) {
    const int c = m0 + wr * 32 + mf * 16 + l4 * 4;
    if (c < CTOT) {
      const float4 bia = *(const float4*)&b_feat[c];
#pragma unroll
      for (int nf = 0; nf < 8; ++nf) {
        const int n = wc * 128 + nf * 16 + l15;
        ushort4 o;
        o.x = f2bf(acc[mf][nf][0] + bia.x);
        o.y = f2bf(acc[mf][nf][1] + bia.y);
        o.z = f2bf(acc[mf][nf][2] + bia.z);
        o.w = f2bf(acc[mf][nf][3] + bia.w);
        *(ushort4*)(featb + (size_t)n * CTOT + c) = o;
      }
    }
  }
}

// ============ Stage B: xinb[tile][pp][i] = bf16(coord_em + w_cd . coord_data)
__global__ __launch_bounds__(256) void coord_prep(
    const float* __restrict__ coord_em, const float* __restrict__ coord_dt,
    const float* __restrict__ w_cd, const float* __restrict__ b_cd,
    unsigned short* __restrict__ xinb) {
  const int gid = blockIdx.x * 256 + threadIdx.x;
  const int b = gid >> 15;
  const int p = gid & 32767;
  const float* __restrict__ cdr = coord_dt + ((size_t)b * PTOT + p) * OUT_CH;
  float acc[IN_CH];
#pragma unroll
  for (int o = 0; o < IN_CH; ++o) acc[o] = 0.f;
  for (int ic = 0; ic < OUT_CH; ic += 16) {
    float x[16];
#pragma unroll
    for (int j = 0; j < 16; j += 4) {
      float4 v = *(const float4*)(cdr + ic + j);
      x[j] = v.x; x[j + 1] = v.y; x[j + 2] = v.z; x[j + 3] = v.w;
    }
#pragma unroll
    for (int o = 0; o < IN_CH; ++o) {
#pragma unroll
      for (int j = 0; j < 16; ++j)
        acc[o] = fmaf(w_cd[o * OUT_CH + ic + j], x[j], acc[o]);
    }
  }
#pragma unroll
  for (int o = 0; o < IN_CH; ++o)
    acc[o] += b_cd[o] + coord_em[((size_t)b * IN_CH + o) * PTOT + p];
  const int s = p >> 12, rem = p & 4095;
  const int oh = rem >> 6, ow = rem & 63;
  const int a = ((oh >> 3) << 3) | (ow >> 3);
  const int pp = (s << 6) | ((oh & 7) << 3) | (ow & 7);
  unsigned short* __restrict__ dst = xinb + ((size_t)((b << 6) + a) * 512 + pp) * IN_CH;
#pragma unroll
  for (int o = 0; o < IN_CH; o += 4) {
    ushort4 v;
    v.x = f2bf(acc[o]);     v.y = f2bf(acc[o + 1]);
    v.z = f2bf(acc[o + 2]); v.w = f2bf(acc[o + 3]);
    *(ushort4*)(dst + o) = v;
  }
}

// ============ Stage C: one block per tile, 4 chunks of 128 rows.
// waves: wr = wv&3 (4 row-groups of 32), wc = wv>>2 (2 col-groups of 128).
__global__ __launch_bounds__(512, 2) void tile_mlp(
    const unsigned short* __restrict__ featb, const unsigned short* __restrict__ xinb,
    float* __restrict__ sc) {
  __shared__ unsigned short xch[128][40];
  __shared__ unsigned short h1[128][264];   // row stride 528B = +4 banks: 2-way on b128 reads (free)
  __shared__ unsigned short h2[128][264];
  const int tile = blockIdx.x;
  const int tid = threadIdx.x;
  const int lane = tid & 63;
  const int wv = tid >> 6;
  const int wr = wv & 3, wc = wv >> 2;
  const int l15 = lane & 15, l4 = lane >> 4;
  const unsigned short* __restrict__ F = featb + (size_t)tile * CTOT;

  float b1[8], b2[8], b3[2];
#pragma unroll
  for (int nf = 0; nf < 8; ++nf) {
    b1[nf] = bf2f(F[BIAS1 + wc * 128 + nf * 16 + l15]);
    b2[nf] = bf2f(F[BIAS2 + wc * 128 + nf * 16 + l15]);
  }
#pragma unroll
  for (int nf = 0; nf < 2; ++nf)
    b3[nf] = bf2f(F[BIAS3 + wc * 32 + nf * 16 + l15]);

  for (int ch = 0; ch < 4; ++ch) {
    const int row0 = ch * 128;
    {  // stage 128 rows x 32 ch bf16: one ushort8 per thread
      const int r = tid >> 2, c8 = (tid & 3) * 8;
      *(ushort8*)&xch[r][c8] =
          *(const ushort8*)(xinb + ((size_t)tile * 512 + row0 + r) * IN_CH + c8);
    }
    __syncthreads();
    // ---- layer 1: 128x256, K=32
    f32x4 a1[2][8];
#pragma unroll
    for (int mf = 0; mf < 2; ++mf)
#pragma unroll
      for (int nf = 0; nf < 8; ++nf) a1[mf][nf] = f32x4{0.f, 0.f, 0.f, 0.f};
    {
      bf16x8 A[2];
#pragma unroll
      for (int mf = 0; mf < 2; ++mf)
        A[mf] = *(const bf16x8*)&xch[wr * 32 + mf * 16 + l15][l4 * 8];
#pragma unroll
      for (int nf = 0; nf < 8; ++nf) {
        const bf16x8 Bv = *(const bf16x8*)(F + BEG1 + (size_t)(wc * 128 + nf * 16 + l15) * 32 + l4 * 8);
#pragma unroll
        for (int mf = 0; mf < 2; ++mf)
          a1[mf][nf] = __builtin_amdgcn_mfma_f32_16x16x32_bf16(A[mf], Bv, a1[mf][nf], 0, 0, 0);
      }
    }
#pragma unroll
    for (int mf = 0; mf < 2; ++mf)
#pragma unroll
      for (int nf = 0; nf < 8; ++nf)
#pragma unroll
        for (int r = 0; r < 4; ++r) {
          float v = a1[mf][nf][r] + b1[nf];
          v = v >= 0.f ? v : 0.01f * v;
          h1[wr * 32 + mf * 16 + l4 * 4 + r][wc * 128 + nf * 16 + l15] = f2bf(v);
        }
    __syncthreads();
    // ---- layer 2: 128x256, K=256
    f32x4 a2[2][8];
#pragma unroll
    for (int mf = 0; mf < 2; ++mf)
#pragma unroll
      for (int nf = 0; nf < 8; ++nf) a2[mf][nf] = f32x4{0.f, 0.f, 0.f, 0.f};
#pragma unroll 2
    for (int ks = 0; ks < 8; ++ks) {
      bf16x8 A2[2];
#pragma unroll
      for (int mf = 0; mf < 2; ++mf)
        A2[mf] = *(const bf16x8*)&h1[wr * 32 + mf * 16 + l15][ks * 32 + l4 * 8];
#pragma unroll
      for (int nf = 0; nf < 8; ++nf) {
        const bf16x8 Bv = *(const bf16x8*)(F + BEG2 + (size_t)(wc * 128 + nf * 16 + l15) * 256 + ks * 32 + l4 * 8);
#pragma unroll
        for (int mf = 0; mf < 2; ++mf)
          a2[mf][nf] = __builtin_amdgcn_mfma_f32_16x16x32_bf16(A2[mf], Bv, a2[mf][nf], 0, 0, 0);
      }
    }
#pragma unroll
    for (int mf = 0; mf < 2; ++mf)
#pragma unroll
      for (int nf = 0; nf < 8; ++nf)
#pragma unroll
        for (int r = 0; r < 4; ++r) {
          float v = a2[mf][nf][r] + b2[nf];
          v = v >= 0.f ? v : 0.01f * v;
          h2[wr * 32 + mf * 16 + l4 * 4 + r][wc * 128 + nf * 16 + l15] = f2bf(v);
        }
    __syncthreads();
    // ---- layer 3: 128x64, K=256 -> sc[tile][row][o] fp32 (contiguous per tile)
    f32x4 a3[2][2];
#pragma unroll
    for (int mf = 0; mf < 2; ++mf)
#pragma unroll
      for (int nf = 0; nf < 2; ++nf) a3[mf][nf] = f32x4{0.f, 0.f, 0.f, 0.f};
#pragma unroll 2
    for (int ks = 0; ks < 8; ++ks) {
      bf16x8 A3[2];
#pragma unroll
      for (int mf = 0; mf < 2; ++mf)
        A3[mf] = *(const bf16x8*)&h2[wr * 32 + mf * 16 + l15][ks * 32 + l4 * 8];
#pragma unroll
      for (int nf = 0; nf < 2; ++nf) {
        const bf16x8 Bv = *(const bf16x8*)(F + BEG3 + (size_t)(wc * 32 + nf * 16 + l15) * 256 + ks * 32 + l4 * 8);
#pragma unroll
        for (int mf = 0; mf < 2; ++mf)
          a3[mf][nf] = __builtin_amdgcn_mfma_f32_16x16x32_bf16(A3[mf], Bv, a3[mf][nf], 0, 0, 0);
      }
    }
#pragma unroll
    for (int mf = 0; mf < 2; ++mf)
#pragma unroll
      for (int nf = 0; nf < 2; ++nf) {
        const int o = wc * 32 + nf * 16 + l15;
#pragma unroll
        for (int r = 0; r < 4; ++r) {
          const int row = row0 + wr * 32 + mf * 16 + l4 * 4 + r;
          sc[((size_t)tile * 512 + row) * 64 + o] = a3[mf][nf][r] + b3[nf];
        }
      }
    __syncthreads();
  }
}

// ============ output transpose: out[b][o][s][oh][ow] from sc[tile][pp][o]
__global__ __launch_bounds__(256) void out_tr(
    const float* __restrict__ sc, float* __restrict__ out) {
  __shared__ float t[64][65];
  const int bid = blockIdx.x;
  const int oh = bid & 63, s = (bid >> 6) & 7, b = bid >> 9;
  const int ah = oh >> 3, ph = oh & 7;
  const int tid = threadIdx.x;
#pragma unroll
  for (int g = 0; g < 4; ++g) {
    const int aw = g * 2 + (tid >> 7);
    const int t7 = tid & 127;
    const int pw = t7 >> 4, o4 = (t7 & 15) * 4;
    const float4 v = *(const float4*)&sc[
        (((size_t)(b * 64 + ah * 8 + aw) * 512) + s * 64 + ph * 8 + pw) * 64 + o4];
    const int ow = aw * 8 + pw;
    t[o4 + 0][ow] = v.x; t[o4 + 1][ow] = v.y;
    t[o4 + 2][ow] = v.z; t[o4 + 3][ow] = v.w;
  }
  __syncthreads();
#pragma unroll
  for (int it = 0; it < 4; ++it) {
    const int o = it * 16 + (tid >> 4);
    const int ow4 = (tid & 15) * 4;
    float4 v;
    v.x = t[o][ow4]; v.y = t[o][ow4 + 1]; v.z = t[o][ow4 + 2]; v.w = t[o][ow4 + 3];
    *(float4*)&out[(((size_t)(b * 64 + o)) * 8 + s) * 4096 + oh * 64 + ow4] = v;
  }
}

extern "C" void kernel_launch(void* const* d_in, const int* in_sizes, int n_in,
                              void* d_out, int out_size, void* d_ws, size_t ws_size,
                              hipStream_t stream) {
  const float* mlp      = (const float*)d_in[0];
  const float* coord_em = (const float*)d_in[1];
  const float* coord_dt = (const float*)d_in[2];
  const float* w_cd     = (const float*)d_in[3];
  const float* b_cd     = (const float*)d_in[4];
  const float* w_feat   = (const float*)d_in[5];
  const float* b_feat   = (const float*)d_in[6];
  float* out = (float*)d_out;
  unsigned short* featb = (unsigned short*)d_ws;                         // 46,432,256
  unsigned short* xinb  = (unsigned short*)((char*)d_ws + 46432256ull);  // 8,388,608
  unsigned short* mlpT  = (unsigned short*)((char*)d_ws + 54820864ull);  // 131,072
  float*          sc    = (float*)((char*)d_ws + 54951936ull);           // 33,554,432

  mlp_tr<<<16, 256, 0, stream>>>(mlp, mlpT);
  coord_prep<<<512, 256, 0, stream>>>(coord_em, coord_dt, w_cd, b_cd, xinb);
  feat_gemm_mfma<<<709, 512, 0, stream>>>(w_feat, b_feat, mlpT, featb);
  tile_mlp<<<256, 512, 0, stream>>>(featb, xinb, sc);
  out_tr<<<2048, 256, 0, stream>>>(sc, out);
}

// Round 4
// 191.917 us; speedup vs baseline: 11.8223x; 1.2937x over previous
//
#include <hip/hip_runtime.h>

typedef __attribute__((ext_vector_type(8))) short bf16x8;
typedef __attribute__((ext_vector_type(8))) unsigned short ushort8;
typedef __attribute__((ext_vector_type(4))) float f32x4;

#define IN_CH   32
#define OUT_CH  64
#define FEAT_CH 256
#define PTOT    32768
#define CTOT    90688
#define BEG1    0
#define BIAS1   8192
#define BEG2    8448
#define BIAS2   73984
#define BEG3    74240
#define BIAS3   90624

__device__ __forceinline__ unsigned short f2bf(float f) {
  __bf16 h = (__bf16)f;
  return __builtin_bit_cast(unsigned short, h);
}
__device__ __forceinline__ float bf2f(unsigned short h) {
  union { unsigned u; float f; } v; v.u = ((unsigned)h) << 16;
  return v.f;
}
__device__ __forceinline__ unsigned pk_bf16(float lo, float hi) {  // D[15:0]=bf16(lo)
  unsigned r;
  asm("v_cvt_pk_bf16_f32 %0, %1, %2" : "=v"(r) : "v"(lo), "v"(hi));
  return r;
}
__device__ __forceinline__ void gload16(const void* g, void* l) {
  __builtin_amdgcn_global_load_lds(
      (const __attribute__((address_space(1))) unsigned int*)g,
      (__attribute__((address_space(3))) unsigned int*)l, 16, 0, 0);
}

// ============ mlp transpose: mlpT[n][k] = bf16(mlp[b][k][a]), n = b*64+a
__global__ __launch_bounds__(256) void mlp_tr(
    const float* __restrict__ mlp, unsigned short* __restrict__ mlpT) {
  __shared__ float t[64][65];
  const int b = blockIdx.x >> 2, k0 = (blockIdx.x & 3) << 6;
  const int tid = threadIdx.x;
  const int a = tid & 63, kq = tid >> 6;
#pragma unroll
  for (int j = 0; j < 16; ++j) {
    const int k = kq * 16 + j;
    t[k][a] = mlp[(size_t)b * 16384 + (size_t)(k0 + k) * 64 + a];
  }
  __syncthreads();
  const int a2 = tid >> 2, c4 = tid & 3;
  ushort8 o0, o1;
#pragma unroll
  for (int j = 0; j < 8; ++j)  o0[j] = f2bf(t[c4 * 16 + j][a2]);
#pragma unroll
  for (int j = 0; j < 8; ++j)  o1[j] = f2bf(t[c4 * 16 + 8 + j][a2]);
  unsigned short* dst = mlpT + (size_t)(b * 64 + a2) * 256 + k0 + c4 * 16;
  *(ushort8*)dst = o0;
  *(ushort8*)(dst + 8) = o1;
}

// ============ Stage A: featb[n][c] = bf16(w_feat[c,:].mlpT[n,:] + b_feat[c])
// async-staged w_feat (fp32) in LDS, double-buffered, source-XOR-swizzled.
__global__ __launch_bounds__(512, 4) void feat_gemm_mfma(
    const float* __restrict__ w_feat, const float* __restrict__ b_feat,
    const unsigned short* __restrict__ mlpT, unsigned short* __restrict__ featb) {
  __shared__ float wbuf[2][128 * 32];     // 16KB per buffer
  const int tid = threadIdx.x;
  const int lane = tid & 63;
  const int wv = tid >> 6;
  const int wr = wv & 3, wc = wv >> 2;
  const int l15 = lane & 15, l4 = lane >> 4;
  const int m0 = blockIdx.x * 128;
  const int sr = lane >> 3, scn = lane & 7;      // staging row/chunk of this lane

  // prologue: stage slice 0
#pragma unroll
  for (int i8 = 0; i8 < 2; ++i8) {
    const int row_l = wv * 16 + i8 * 8 + sr;
    int grow = m0 + row_l; if (grow > CTOT - 1) grow = CTOT - 1;
    gload16(w_feat + (size_t)grow * 256 + ((scn ^ (row_l & 7)) << 2),
            &wbuf[0][(wv * 16 + i8 * 8) * 32]);
  }
  __syncthreads();

  f32x4 acc[2][8];
#pragma unroll
  for (int mf = 0; mf < 2; ++mf)
#pragma unroll
    for (int nf = 0; nf < 8; ++nf) acc[mf][nf] = f32x4{0.f, 0.f, 0.f, 0.f};

#pragma unroll 1
  for (int ks = 0; ks < 8; ++ks) {
    const int buf = ks & 1;
    if (ks < 7) {   // issue next slice into other buffer (overlaps compute)
#pragma unroll
      for (int i8 = 0; i8 < 2; ++i8) {
        const int row_l = wv * 16 + i8 * 8 + sr;
        int grow = m0 + row_l; if (grow > CTOT - 1) grow = CTOT - 1;
        gload16(w_feat + (size_t)grow * 256 + (ks + 1) * 32 + ((scn ^ (row_l & 7)) << 2),
                &wbuf[buf ^ 1][(wv * 16 + i8 * 8) * 32]);
      }
    }
    bf16x8 A[2];
#pragma unroll
    for (int mf = 0; mf < 2; ++mf) {
      const int row_l = wr * 32 + mf * 16 + l15;
      const int q0 = (2 * l4) ^ (row_l & 7), q1 = (2 * l4 + 1) ^ (row_l & 7);
      const float4 p0 = *(const float4*)&wbuf[buf][row_l * 32 + q0 * 4];
      const float4 p1 = *(const float4*)&wbuf[buf][row_l * 32 + q1 * 4];
      unsigned u0 = pk_bf16(p0.x, p0.y), u1 = pk_bf16(p0.z, p0.w);
      unsigned u2 = pk_bf16(p1.x, p1.y), u3 = pk_bf16(p1.z, p1.w);
      unsigned t[4] = {u0, u1, u2, u3};
      A[mf] = __builtin_bit_cast(bf16x8, *(ulonglong2*)t);
    }
#pragma unroll
    for (int nf = 0; nf < 8; ++nf) {
      const bf16x8 Bv = *(const bf16x8*)(mlpT + (size_t)(wc * 128 + nf * 16 + l15) * 256 + ks * 32 + l4 * 8);
#pragma unroll
      for (int mf = 0; mf < 2; ++mf)
        acc[mf][nf] = __builtin_amdgcn_mfma_f32_16x16x32_bf16(A[mf], Bv, acc[mf][nf], 0, 0, 0);
    }
    __syncthreads();   // staging complete + all reads of buf done
  }

#pragma unroll
  for (int mf = 0; mf < 2; ++mf) {
    const int c = m0 + wr * 32 + mf * 16 + l4 * 4;
    if (c < CTOT) {
      const float4 bia = *(const float4*)&b_feat[c];
#pragma unroll
      for (int nf = 0; nf < 8; ++nf) {
        const int n = wc * 128 + nf * 16 + l15;
        ushort4 o;
        o.x = f2bf(acc[mf][nf][0] + bia.x);
        o.y = f2bf(acc[mf][nf][1] + bia.y);
        o.z = f2bf(acc[mf][nf][2] + bia.z);
        o.w = f2bf(acc[mf][nf][3] + bia.w);
        *(ushort4*)(featb + (size_t)n * CTOT + c) = o;
      }
    }
  }
}

// ============ Stage B: xinb[tile][pp][i] = bf16(coord_em + w_cd . coord_data)
__global__ __launch_bounds__(256) void coord_prep(
    const float* __restrict__ coord_em, const float* __restrict__ coord_dt,
    const float* __restrict__ w_cd, const float* __restrict__ b_cd,
    unsigned short* __restrict__ xinb) {
  const int gid = blockIdx.x * 256 + threadIdx.x;
  const int b = gid >> 15;
  const int p = gid & 32767;
  const float* __restrict__ cdr = coord_dt + ((size_t)b * PTOT + p) * OUT_CH;
  float acc[IN_CH];
#pragma unroll
  for (int o = 0; o < IN_CH; ++o) acc[o] = 0.f;
  for (int ic = 0; ic < OUT_CH; ic += 16) {
    float x[16];
#pragma unroll
    for (int j = 0; j < 16; j += 4) {
      float4 v = *(const float4*)(cdr + ic + j);
      x[j] = v.x; x[j + 1] = v.y; x[j + 2] = v.z; x[j + 3] = v.w;
    }
#pragma unroll
    for (int o = 0; o < IN_CH; ++o) {
#pragma unroll
      for (int j = 0; j < 16; ++j)
        acc[o] = fmaf(w_cd[o * OUT_CH + ic + j], x[j], acc[o]);
    }
  }
#pragma unroll
  for (int o = 0; o < IN_CH; ++o)
    acc[o] += b_cd[o] + coord_em[((size_t)b * IN_CH + o) * PTOT + p];
  const int s = p >> 12, rem = p & 4095;
  const int oh = rem >> 6, ow = rem & 63;
  const int a = ((oh >> 3) << 3) | (ow >> 3);
  const int pp = (s << 6) | ((oh & 7) << 3) | (ow & 7);
  unsigned short* __restrict__ dst = xinb + ((size_t)((b << 6) + a) * 512 + pp) * IN_CH;
#pragma unroll
  for (int o = 0; o < IN_CH; o += 4) {
    ushort4 v;
    v.x = f2bf(acc[o]);     v.y = f2bf(acc[o + 1]);
    v.z = f2bf(acc[o + 2]); v.w = f2bf(acc[o + 3]);
    *(ushort4*)(dst + o) = v;
  }
}

// ============ Stage C: swapped-operand MFMA MLP. Block = half tile (256 px), 2 chunks of 128.
// Waves: wr = wv&3 (channel group of 64), wc = wv>>2 (pixel group of 64).
// D = mfma(W, X): lane holds pixel=l15, 4 consecutive channels per reg quad.
__global__ __launch_bounds__(512, 4) void tile_mlp(
    const unsigned short* __restrict__ featb, const unsigned short* __restrict__ xinb,
    float* __restrict__ sc) {
  __shared__ unsigned short h[128][264];   // 67.6KB, row stride 528B (2-way banks: free)
  const int blk = blockIdx.x;
  const int tile = blk >> 1, half = blk & 1;
  const int tid = threadIdx.x;
  const int lane = tid & 63;
  const int wv = tid >> 6;
  const int wr = wv & 3, wc = wv >> 2;
  const int l15 = lane & 15, l4 = lane >> 4;
  const unsigned short* __restrict__ F = featb + (size_t)tile * CTOT;

  for (int ch2 = 0; ch2 < 2; ++ch2) {
    const int p0 = half * 256 + ch2 * 128;
    // ---- layer 1: [256 ch] x [128 px], K=32
    f32x4 a1[4][4];
#pragma unroll
    for (int mf = 0; mf < 4; ++mf) {
      const ushort4 bq = *(const ushort4*)(F + BIAS1 + wr * 64 + mf * 16 + l4 * 4);
      const f32x4 bi = {bf2f(bq.x), bf2f(bq.y), bf2f(bq.z), bf2f(bq.w)};
#pragma unroll
      for (int nf = 0; nf < 4; ++nf) a1[mf][nf] = bi;
    }
    {
      bf16x8 W1[4];
#pragma unroll
      for (int mf = 0; mf < 4; ++mf)
        W1[mf] = *(const bf16x8*)(F + BEG1 + (size_t)(wr * 64 + mf * 16 + l15) * 32 + l4 * 8);
#pragma unroll
      for (int nf = 0; nf < 4; ++nf) {
        const bf16x8 X1 = *(const bf16x8*)(xinb +
            ((size_t)tile * 512 + p0 + wc * 64 + nf * 16 + l15) * IN_CH + l4 * 8);
#pragma unroll
        for (int mf = 0; mf < 4; ++mf)
          a1[mf][nf] = __builtin_amdgcn_mfma_f32_16x16x32_bf16(W1[mf], X1, a1[mf][nf], 0, 0, 0);
      }
    }
    // epilogue: leaky-relu + pack -> h[pixel][channel]
#pragma unroll
    for (int mf = 0; mf < 4; ++mf)
#pragma unroll
      for (int nf = 0; nf < 4; ++nf) {
        float v0 = a1[mf][nf][0]; v0 = fmaxf(v0, 0.01f * v0);
        float v1 = a1[mf][nf][1]; v1 = fmaxf(v1, 0.01f * v1);
        float v2 = a1[mf][nf][2]; v2 = fmaxf(v2, 0.01f * v2);
        float v3 = a1[mf][nf][3]; v3 = fmaxf(v3, 0.01f * v3);
        uint2 pk; pk.x = pk_bf16(v0, v1); pk.y = pk_bf16(v2, v3);
        *(uint2*)&h[wc * 64 + nf * 16 + l15][wr * 64 + mf * 16 + l4 * 4] = pk;
      }
    __syncthreads();
    // ---- layer 2: [256 ch] x [128 px], K=256
    f32x4 a2[4][4];
#pragma unroll
    for (int mf = 0; mf < 4; ++mf) {
      const ushort4 bq = *(const ushort4*)(F + BIAS2 + wr * 64 + mf * 16 + l4 * 4);
      const f32x4 bi = {bf2f(bq.x), bf2f(bq.y), bf2f(bq.z), bf2f(bq.w)};
#pragma unroll
      for (int nf = 0; nf < 4; ++nf) a2[mf][nf] = bi;
    }
#pragma unroll 2
    for (int ks = 0; ks < 8; ++ks) {
      bf16x8 W2[4];
#pragma unroll
      for (int mf = 0; mf < 4; ++mf)
        W2[mf] = *(const bf16x8*)(F + BEG2 + (size_t)(wr * 64 + mf * 16 + l15) * 256 + ks * 32 + l4 * 8);
#pragma unroll
      for (int nf = 0; nf < 4; ++nf) {
        const bf16x8 X2 = *(const bf16x8*)&h[wc * 64 + nf * 16 + l15][ks * 32 + l4 * 8];
#pragma unroll
        for (int mf = 0; mf < 4; ++mf)
          a2[mf][nf] = __builtin_amdgcn_mfma_f32_16x16x32_bf16(W2[mf], X2, a2[mf][nf], 0, 0, 0);
      }
    }
    __syncthreads();   // all h reads done before overwrite
#pragma unroll
    for (int mf = 0; mf < 4; ++mf)
#pragma unroll
      for (int nf = 0; nf < 4; ++nf) {
        float v0 = a2[mf][nf][0]; v0 = fmaxf(v0, 0.01f * v0);
        float v1 = a2[mf][nf][1]; v1 = fmaxf(v1, 0.01f * v1);
        float v2 = a2[mf][nf][2]; v2 = fmaxf(v2, 0.01f * v2);
        float v3 = a2[mf][nf][3]; v3 = fmaxf(v3, 0.01f * v3);
        uint2 pk; pk.x = pk_bf16(v0, v1); pk.y = pk_bf16(v2, v3);
        *(uint2*)&h[wc * 64 + nf * 16 + l15][wr * 64 + mf * 16 + l4 * 4] = pk;
      }
    __syncthreads();
    // ---- layer 3: [64 ch] x [128 px], K=256 -> sc fp32 float4 stores
    f32x4 a3[4];
    {
      const ushort4 bq = *(const ushort4*)(F + BIAS3 + wr * 16 + l4 * 4);
      const f32x4 bi = {bf2f(bq.x), bf2f(bq.y), bf2f(bq.z), bf2f(bq.w)};
#pragma unroll
      for (int nf = 0; nf < 4; ++nf) a3[nf] = bi;
    }
#pragma unroll 2
    for (int ks = 0; ks < 8; ++ks) {
      const bf16x8 W3 = *(const bf16x8*)(F + BEG3 + (size_t)(wr * 16 + l15) * 256 + ks * 32 + l4 * 8);
#pragma unroll
      for (int nf = 0; nf < 4; ++nf) {
        const bf16x8 X3 = *(const bf16x8*)&h[wc * 64 + nf * 16 + l15][ks * 32 + l4 * 8];
        a3[nf] = __builtin_amdgcn_mfma_f32_16x16x32_bf16(W3, X3, a3[nf], 0, 0, 0);
      }
    }
#pragma unroll
    for (int nf = 0; nf < 4; ++nf) {
      const int p = p0 + wc * 64 + nf * 16 + l15;
      float4 v; v.x = a3[nf][0]; v.y = a3[nf][1]; v.z = a3[nf][2]; v.w = a3[nf][3];
      *(float4*)&sc[((size_t)tile * 512 + p) * 64 + wr * 16 + l4 * 4] = v;
    }
    __syncthreads();   // h reads done before next chunk's layer-1 writes
  }
}

// ============ output transpose: out[b][o][s][oh][ow] from sc[tile][pp][o]
__global__ __launch_bounds__(256) void out_tr(
    const float* __restrict__ sc, float* __restrict__ out) {
  __shared__ float t[64][65];
  const int bid = blockIdx.x;
  const int oh = bid & 63, s = (bid >> 6) & 7, b = bid >> 9;
  const int ah = oh >> 3, ph = oh & 7;
  const int tid = threadIdx.x;
#pragma unroll
  for (int g = 0; g < 4; ++g) {
    const int aw = g * 2 + (tid >> 7);
    const int t7 = tid & 127;
    const int pw = t7 >> 4, o4 = (t7 & 15) * 4;
    const float4 v = *(const float4*)&sc[
        (((size_t)(b * 64 + ah * 8 + aw) * 512) + s * 64 + ph * 8 + pw) * 64 + o4];
    const int ow = aw * 8 + pw;
    t[o4 + 0][ow] = v.x; t[o4 + 1][ow] = v.y;
    t[o4 + 2][ow] = v.z; t[o4 + 3][ow] = v.w;
  }
  __syncthreads();
#pragma unroll
  for (int it = 0; it < 4; ++it) {
    const int o = it * 16 + (tid >> 4);
    const int ow4 = (tid & 15) * 4;
    float4 v;
    v.x = t[o][ow4]; v.y = t[o][ow4 + 1]; v.z = t[o][ow4 + 2]; v.w = t[o][ow4 + 3];
    *(float4*)&out[(((size_t)(b * 64 + o)) * 8 + s) * 4096 + oh * 64 + ow4] = v;
  }
}

extern "C" void kernel_launch(void* const* d_in, const int* in_sizes, int n_in,
                              void* d_out, int out_size, void* d_ws, size_t ws_size,
                              hipStream_t stream) {
  const float* mlp      = (const float*)d_in[0];
  const float* coord_em = (const float*)d_in[1];
  const float* coord_dt = (const float*)d_in[2];
  const float* w_cd     = (const float*)d_in[3];
  const float* b_cd     = (const float*)d_in[4];
  const float* w_feat   = (const float*)d_in[5];
  const float* b_feat   = (const float*)d_in[6];
  float* out = (float*)d_out;
  unsigned short* featb = (unsigned short*)d_ws;                         // 46,432,256
  unsigned short* xinb  = (unsigned short*)((char*)d_ws + 46432256ull);  // 8,388,608
  unsigned short* mlpT  = (unsigned short*)((char*)d_ws + 54820864ull);  // 131,072
  float*          sc    = (float*)((char*)d_ws + 54951936ull);           // 33,554,432

  mlp_tr<<<16, 256, 0, stream>>>(mlp, mlpT);
  coord_prep<<<512, 256, 0, stream>>>(coord_em, coord_dt, w_cd, b_cd, xinb);
  feat_gemm_mfma<<<709, 512, 0, stream>>>(w_feat, b_feat, mlpT, featb);
  tile_mlp<<<512, 512, 0, stream>>>(featb, xinb, sc);
  out_tr<<<2048, 256, 0, stream>>>(sc, out);
}